// Round 5
// baseline (476.392 us; speedup 1.0000x reference)
//
#include <hip/hip_runtime.h>
#include <hip/hip_bf16.h>
#include <math.h>

#define D_MODEL 2048
#define NUM_HEADS 16
#define D_K 128
#define SEQ_LEN 4096
#define BATCH 4
#define M_ROWS 16384          // BATCH*SEQ_LEN
#define N_TOT 2304            // 2048 (Q) + 128 (K) + 128 (V)
#define KT 32                 // K-tiles of 64 (2048/64)

#define XB_BYTES 67108864ull  // [64 mb][32 kt][32KB tile] x bf16, swizzled LDS image
#define WT_BYTES 9437184ull   // [9 nb2][32 kt][32KB tile] W bf16, stripe-permuted, swizzled
#define BP_BYTES 16384ull     // permuted bias

typedef __attribute__((ext_vector_type(8))) short bf16x8;
typedef __attribute__((ext_vector_type(8))) unsigned short u16x8;
typedef __attribute__((ext_vector_type(16))) float f32x16;

__device__ __forceinline__ unsigned short f2bf(float f) {
  unsigned int u = __builtin_bit_cast(unsigned int, f);
  u += 0x7fffu + ((u >> 16) & 1u);
  return (unsigned short)(u >> 16);
}

__device__ __forceinline__ void async16(const unsigned char* g, unsigned char* l) {
  __builtin_amdgcn_global_load_lds(
      (const __attribute__((address_space(1))) void*)g,
      (__attribute__((address_space(3))) void*)l, 16, 0, 0);
}

// ---------------- rope coefficient table ----------------
__global__ void rope_kernel(float* __restrict__ ropeT) {
  int idx = blockIdx.x * 256 + threadIdx.x;   // 262144 = 4096*64
  int o = idx & 63;
  int sp = idx >> 6;
  int j1 = (o < 32) ? (2 * o) : (2 * (o - 32));
  float th1 = 1.0f / powf(10000.0f, (float)j1 / 64.0f);
  float th2 = 1.0f / powf(10000.0f, (float)(j1 + 1) / 64.0f);
  float a1 = (float)sp * th1;
  float a2 = (float)sp * th2;
  float v1 = (o < 32) ? sinf(a1) : cosf(a1);
  float v2 = (o < 32) ? sinf(a2) : cosf(a2);
  const float sc = 11.3137084989847604f; // sqrt(128)
  ropeT[sp * 128 + o]      = v1 * sc;
  ropeT[sp * 128 + 64 + o] = v2 * sc;
}

// ---------------- permuted bias ----------------
__global__ void bias_kernel(const float* __restrict__ bq, const float* __restrict__ bk,
                            const float* __restrict__ bv, float* __restrict__ bp) {
  int n = blockIdx.x * 256 + threadIdx.x;   // 2304
  if (n >= N_TOT) return;
  int r = n & 127, nb = n >> 7;
  int d = (r < 64) ? (2 * r) : (2 * (r - 64) + 1);
  float v;
  if (nb < 16)       v = bq[nb * 128 + d];
  else if (nb == 16) v = bk[d];
  else               v = bv[d];
  bp[n] = v;
}

// ---------------- W -> bf16, stripe-permuted cols (32x32 wave tiling), swizzled ----------------
// tile(nb2,kt): 256 LDS-rows x 8 chunks of 16B. LDS-row R = wng*64 + j*32 + c31:
//   opfull = (wng&1)*32 + j*64 + c31 ; s = wng>>1 ; d = even/odd(opfull)
//   n = (nb2*2+s)*128 + d ; chunk c (k-octet of K64) stored at c ^ (R&7)
__global__ void wsplit_kernel(const float* __restrict__ Wq, const float* __restrict__ Wk,
                              const float* __restrict__ Wv, unsigned char* __restrict__ wt) {
  int R = threadIdx.x;
  int c   = blockIdx.x & 7;
  int kt  = (blockIdx.x >> 3) & 31;
  int nb2 = blockIdx.x >> 8;         // grid = 9*256
  int wng = R >> 6, j = (R >> 5) & 1, c31 = R & 31;
  int opfull = (wng & 1) * 32 + j * 64 + c31;
  int s = wng >> 1;
  int d = (opfull < 64) ? (2 * opfull) : (2 * (opfull - 64) + 1);
  int n = (nb2 * 2 + s) * 128 + d;
  const float* src; int ld, cc;
  if (n < 2048)      { src = Wq; ld = 2048; cc = n; }
  else if (n < 2176) { src = Wk; ld = 128;  cc = n - 2048; }
  else               { src = Wv; ld = 128;  cc = n - 2176; }
  int k0 = kt * 64 + c * 8;
  u16x8 H;
#pragma unroll
  for (int jj = 0; jj < 8; jj++) H[jj] = f2bf(src[(size_t)(k0 + jj) * ld + cc]);
  unsigned char* tile = wt + (((size_t)(nb2 * 32 + kt)) << 15);
  *(u16x8*)(tile + R * 128 + ((c ^ (R & 7)) << 4)) = H;
}

// ---------------- x -> bf16, tiled+swizzled ----------------
__global__ void xcast_kernel(const float* __restrict__ x, unsigned char* __restrict__ xb) {
  int idx = blockIdx.x * 256 + threadIdx.x;  // 4,194,304 = 64*32*256*8
  int c  = idx & 7;
  int r  = (idx >> 3) & 255;
  int kt = (idx >> 11) & 31;
  int mb = idx >> 16;
  const float4* p = (const float4*)(x + ((size_t)(mb * 256 + r)) * D_MODEL + kt * 64 + c * 8);
  float4 v0 = p[0], v1 = p[1];
  float v[8] = {v0.x, v0.y, v0.z, v0.w, v1.x, v1.y, v1.z, v1.w};
  u16x8 H;
#pragma unroll
  for (int jj = 0; jj < 8; jj++) H[jj] = f2bf(v[jj]);
  unsigned char* tile = xb + (((size_t)(mb * 32 + kt)) << 15);
  *(u16x8*)(tile + r * 128 + ((c ^ (r & 7)) << 4)) = H;
}

// ---------------- main: 256x256x64, 8 waves, 32x32x16 MFMA, 1 barrier/K-tile ----------------
// Per tile: issue all 8 gloads for t+1 right after the entry barrier (slack ~ full tile),
// read 24 frags + 32 MFMA, then vmcnt(0) (already satisfied) + single barrier.
__global__ __launch_bounds__(512, 2)
void gemm_rope_kernel(const unsigned char* __restrict__ xb,
                      const unsigned char* __restrict__ wt,
                      const float* __restrict__ bp,
                      const float* __restrict__ ropeT,
                      float* __restrict__ out) {
  __shared__ __align__(16) unsigned char lds[131072];  // 2 slots x (A 32K | B 32K)

  const int tid = threadIdx.x;
  const int wave = tid >> 6, lane = tid & 63;
  const int c31 = lane & 31, h = lane >> 5;
  const int wm = wave >> 2;     // 0..1: 128-row band
  const int wng = wave & 3;     // 0..3: 64-col stripe

  int bid = blockIdx.x;                      // 576 = 8 * 72 (bijective XCD swizzle)
  int wg = (bid & 7) * 72 + (bid >> 3);
  const int mb  = wg / 9;
  const int nb2 = wg % 9;

  // fragment LDS byte offsets: slot(row,q,h) = (2q+h) ^ (row&7)  -> uniform 8 lanes/slot
  int aoff[4][4], boff[2][4];
#pragma unroll
  for (int i = 0; i < 4; i++) {
    int row = wm * 128 + i * 32 + c31;
#pragma unroll
    for (int q = 0; q < 4; q++)
      aoff[i][q] = row * 128 + (((2 * q + h) ^ (row & 7)) << 4);
  }
#pragma unroll
  for (int j = 0; j < 2; j++) {
    int rowb = wng * 64 + j * 32 + c31;
#pragma unroll
    for (int q = 0; q < 4; q++)
      boff[j][q] = 32768 + rowb * 128 + (((2 * q + h) ^ (rowb & 7)) << 4);
  }

  f32x16 acc[4][2];
#pragma unroll
  for (int i = 0; i < 4; i++)
#pragma unroll
    for (int j = 0; j < 2; j++)
#pragma unroll
      for (int r = 0; r < 16; r++) acc[i][j][r] = 0.f;

  const unsigned char* gA = xb + ((size_t)(mb * KT) << 15);
  const unsigned char* gB = wt + ((size_t)(nb2 * KT) << 15);
  const int aro = wm * 16384 + wng * 1024;   // A shares: + j*4096
  const int bro = wng * 8192 + wm * 4096;    // B shares: + j*1024 (LDS at +32768)

#define ISSUE(tt)                                                              \
  do {                                                                         \
    const unsigned char* gA_ = gA + ((size_t)(tt) << 15) + aro + lane * 16;    \
    const unsigned char* gB_ = gB + ((size_t)(tt) << 15) + bro + lane * 16;    \
    unsigned char* lA_ = lds + (((tt) & 1) << 16) + aro;                       \
    unsigned char* lB_ = lds + (((tt) & 1) << 16) + 32768 + bro;               \
    async16(gA_,         lA_);                                                 \
    async16(gA_ + 4096,  lA_ + 4096);                                          \
    async16(gA_ + 8192,  lA_ + 8192);                                          \
    async16(gA_ + 12288, lA_ + 12288);                                         \
    async16(gB_,         lB_);                                                 \
    async16(gB_ + 1024,  lB_ + 1024);                                          \
    async16(gB_ + 2048,  lB_ + 2048);                                          \
    async16(gB_ + 3072,  lB_ + 3072);                                          \
  } while (0)

  // prologue: stage tile 0, drain, sync
  ISSUE(0);
  asm volatile("s_waitcnt vmcnt(0)" ::: "memory");
  __builtin_amdgcn_s_barrier();
  __builtin_amdgcn_sched_barrier(0);

  for (int t = 0; t < KT; ++t) {
    if (t + 1 < KT) ISSUE(t + 1);          // ~full-tile slack before the drain below
    const unsigned char* sl = lds + ((t & 1) << 16);
#pragma unroll
    for (int q = 0; q < 4; ++q) {
      bf16x8 A0 = *(const bf16x8*)(sl + aoff[0][q]);
      bf16x8 A1 = *(const bf16x8*)(sl + aoff[1][q]);
      bf16x8 A2 = *(const bf16x8*)(sl + aoff[2][q]);
      bf16x8 A3 = *(const bf16x8*)(sl + aoff[3][q]);
      bf16x8 B0 = *(const bf16x8*)(sl + boff[0][q]);
      bf16x8 B1 = *(const bf16x8*)(sl + boff[1][q]);
      __builtin_amdgcn_s_setprio(1);
      acc[0][0] = __builtin_amdgcn_mfma_f32_32x32x16_bf16(A0, B0, acc[0][0], 0, 0, 0);
      acc[0][1] = __builtin_amdgcn_mfma_f32_32x32x16_bf16(A0, B1, acc[0][1], 0, 0, 0);
      acc[1][0] = __builtin_amdgcn_mfma_f32_32x32x16_bf16(A1, B0, acc[1][0], 0, 0, 0);
      acc[1][1] = __builtin_amdgcn_mfma_f32_32x32x16_bf16(A1, B1, acc[1][1], 0, 0, 0);
      acc[2][0] = __builtin_amdgcn_mfma_f32_32x32x16_bf16(A2, B0, acc[2][0], 0, 0, 0);
      acc[2][1] = __builtin_amdgcn_mfma_f32_32x32x16_bf16(A2, B1, acc[2][1], 0, 0, 0);
      acc[3][0] = __builtin_amdgcn_mfma_f32_32x32x16_bf16(A3, B0, acc[3][0], 0, 0, 0);
      acc[3][1] = __builtin_amdgcn_mfma_f32_32x32x16_bf16(A3, B1, acc[3][1], 0, 0, 0);
      __builtin_amdgcn_s_setprio(0);
    }
    __builtin_amdgcn_sched_barrier(0);
    asm volatile("s_waitcnt vmcnt(0)" ::: "memory");
    __builtin_amdgcn_s_barrier();
    __builtin_amdgcn_sched_barrier(0);
  }
#undef ISSUE

  // epilogue: bias + RoPE; pair (op, op+64) = acc[i][0][r] / acc[i][1][r], same lane
  // C/D map (32x32): col = lane&31, row = (r&3) + 8*(r>>2) + 4*h
  const int m0 = mb * 256 + wm * 128;
  const int op = (wng & 1) * 32 + c31;       // o' in [0,64)
  const int nbv = nb2 * 2 + (wng >> 1);      // 128-col block 0..17
  const int nlo = nbv * 128 + op;
  const float blo = bp[nlo], bhi = bp[nlo + 64];
#pragma unroll
  for (int i = 0; i < 4; i++) {
#pragma unroll
    for (int r = 0; r < 16; r++) {
      int row = m0 + i * 32 + 4 * h + (r & 3) + 8 * (r >> 2);
      int sp = row & (SEQ_LEN - 1);
      int b = row >> 12;
      float t1 = acc[i][0][r] + blo;
      float t2 = acc[i][1][r] + bhi;
      float R1 = ropeT[sp * 128 + op];
      float R2 = ropeT[sp * 128 + 64 + op];
      float olo = R1 * t1 - R2 * t2;
      float ohi = R2 * t1 + R1 * t2;
      size_t base;
      if (nbv < 16)       base = (((size_t)(b * NUM_HEADS + nbv)) * SEQ_LEN + sp) * D_K;
      else if (nbv == 16) base = (size_t)M_ROWS * D_MODEL
                                 + ((size_t)(b * SEQ_LEN + sp)) * D_K;
      else                base = (size_t)M_ROWS * D_MODEL + (size_t)M_ROWS * D_K
                                 + ((size_t)(b * SEQ_LEN + sp)) * D_K;
      out[base + op]      = olo;
      out[base + op + 64] = ohi;
    }
  }
}

extern "C" void kernel_launch(void* const* d_in, const int* in_sizes, int n_in,
                              void* d_out, int out_size, void* d_ws, size_t ws_size,
                              hipStream_t stream) {
  const float* x  = (const float*)d_in[0];
  const float* Wq = (const float*)d_in[1];
  const float* bq = (const float*)d_in[2];
  const float* Wk = (const float*)d_in[3];
  const float* bk = (const float*)d_in[4];
  const float* Wv = (const float*)d_in[5];
  const float* bv = (const float*)d_in[6];
  float* out = (float*)d_out;

  unsigned char* ws = (unsigned char*)d_ws;
  unsigned char* xb = ws;
  unsigned char* wt = ws + XB_BYTES;
  float* bp    = (float*)(ws + XB_BYTES + WT_BYTES);
  float* ropeT = (float*)(ws + XB_BYTES + WT_BYTES + BP_BYTES);
  // ws needed: ~79 MB

  rope_kernel<<<1024, 256, 0, stream>>>(ropeT);
  bias_kernel<<<9, 256, 0, stream>>>(bq, bk, bv, bp);
  wsplit_kernel<<<2304, 256, 0, stream>>>(Wq, Wk, Wv, wt);
  xcast_kernel<<<16384, 256, 0, stream>>>(x, xb);
  gemm_rope_kernel<<<576, 512, 0, stream>>>(xb, wt, bp, ropeT, out);
}